// Round 1
// baseline (553.794 us; speedup 1.0000x reference)
//
#include <hip/hip_runtime.h>

// LJ constants from reference
#define C_CONST 1.0f
#define RC_CONST 1.0f
#define GAMMA 0.1f
#define MIN_R 0.1f

// out[i] = -GAMMA * v[i]  (must init every launch: harness poisons d_out)
__global__ void init_out_kernel(const float* __restrict__ v,
                                float* __restrict__ out, int n) {
    int i = blockIdx.x * blockDim.x + threadIdx.x;
    if (i < n) out[i] = -GAMMA * v[i];
}

__device__ __forceinline__ void do_edge(const float* __restrict__ x,
                                        int s, int d,
                                        float* __restrict__ out) {
    float xs0 = x[3 * s + 0], xs1 = x[3 * s + 1], xs2 = x[3 * s + 2];
    float xd0 = x[3 * d + 0], xd1 = x[3 * d + 1], xd2 = x[3 * d + 2];
    float dx = xd0 - xs0;
    float dy = xd1 - xs1;
    float dz = xd2 - xs2;
    float r2 = dx * dx + dy * dy + dz * dz;
    float r = sqrtf(r2);
    // unit vector: dr / max(r, 1e-12)
    float inv_norm = 1.0f / fmaxf(r, 1e-12f);
    // lj_force with r clamped at MIN_R
    float rc = fmaxf(r, MIN_R);
    float s1 = RC_CONST / rc;            // = 1/rc
    float s2 = s1 * s1;
    float s6 = s2 * s2 * s2;             // s^6
    // F = 4*C*s^6*(12*s^6 - 6)/rc  ; note 1/rc == s1 (RC=1)
    float F = 4.0f * C_CONST * s6 * (12.0f * s6 - 6.0f) * s1;
    float scale = F * inv_norm;
    unsafeAtomicAdd(&out[3 * d + 0], scale * dx);
    unsafeAtomicAdd(&out[3 * d + 1], scale * dy);
    unsafeAtomicAdd(&out[3 * d + 2], scale * dz);
}

__global__ void edge_kernel(const float* __restrict__ x,
                            const int* __restrict__ src,
                            const int* __restrict__ dst,
                            float* __restrict__ out, int n_edges) {
    int t = blockIdx.x * blockDim.x + threadIdx.x;
    int base = t * 4;
    if (base + 3 < n_edges) {
        int4 s4 = *(const int4*)(src + base);
        int4 d4 = *(const int4*)(dst + base);
        do_edge(x, s4.x, d4.x, out);
        do_edge(x, s4.y, d4.y, out);
        do_edge(x, s4.z, d4.z, out);
        do_edge(x, s4.w, d4.w, out);
    } else {
        for (int e = base; e < n_edges; ++e) {
            do_edge(x, src[e], dst[e], out);
        }
    }
}

extern "C" void kernel_launch(void* const* d_in, const int* in_sizes, int n_in,
                              void* d_out, int out_size, void* d_ws, size_t ws_size,
                              hipStream_t stream) {
    const float* x   = (const float*)d_in[0];
    const float* v   = (const float*)d_in[1];
    const int*   src = (const int*)d_in[2];
    const int*   dst = (const int*)d_in[3];
    float* out = (float*)d_out;

    int n_out = out_size;              // n_nodes * 3
    int n_edges = in_sizes[2];

    int blk = 256;
    int grid_init = (n_out + blk - 1) / blk;
    init_out_kernel<<<grid_init, blk, 0, stream>>>(v, out, n_out);

    int n_t = (n_edges + 3) / 4;
    int grid_edge = (n_t + blk - 1) / blk;
    edge_kernel<<<grid_edge, blk, 0, stream>>>(x, src, dst, out, n_edges);
}

// Round 2
// 202.825 us; speedup vs baseline: 2.7304x; 2.7304x over previous
//
#include <hip/hip_runtime.h>

// LJ constants from reference
#define GAMMA 0.1f
#define MIN_R 0.1f

// Binned-scatter parameters
#define NR 5120                 // nodes per range
#define S3 (3 * NR)             // floats per LDS slab (61440 B = 60 KB)

__device__ __forceinline__ float3 lj_msg(const float* __restrict__ x, int s, int d) {
    float dx = x[3 * d + 0] - x[3 * s + 0];
    float dy = x[3 * d + 1] - x[3 * s + 1];
    float dz = x[3 * d + 2] - x[3 * s + 2];
    float r2 = dx * dx + dy * dy + dz * dz;
    float r = sqrtf(r2);
    float inv_norm = 1.0f / fmaxf(r, 1e-12f);   // unit-vector denom
    float rc = fmaxf(r, MIN_R);                 // clamp for force
    float s1 = 1.0f / rc;                       // RC=1 -> s = 1/rc
    float s2 = s1 * s1;
    float s6 = s2 * s2 * s2;
    float F = 4.0f * s6 * (12.0f * s6 - 6.0f) * s1;   // 4*C*s^6*(P*s^6-Q)/rc
    float sc = F * inv_norm;
    return make_float3(sc * dx, sc * dy, sc * dz);
}

// grid = (bpr, R). Block (b, r): scan edge slice b, accumulate dst-in-range-r
// messages into LDS, dump slab to ws[(r*bpr+b)*S3 ...].
__global__ __launch_bounds__(1024) void edge_bin_kernel(
    const float* __restrict__ x,
    const int* __restrict__ src,
    const int* __restrict__ dst,
    float* __restrict__ ws,
    int n_edges, int epb)
{
    __shared__ __align__(16) float acc[S3];
    const int b = blockIdx.x;
    const int r = blockIdx.y;
    const int tid = threadIdx.x;

    for (int i = tid; i < S3; i += 1024) acc[i] = 0.0f;
    __syncthreads();

    const int lo = r * NR;
    const int slice_start = b * epb;                       // epb is a multiple of 4
    const int slice_end = min(slice_start + epb, n_edges);

    for (int base = slice_start + tid * 4; base < slice_end; base += 1024 * 4) {
        if (base + 3 < slice_end) {
            int4 d4 = *(const int4*)(dst + base);
            #pragma unroll
            for (int k = 0; k < 4; ++k) {
                int d = (k == 0) ? d4.x : (k == 1) ? d4.y : (k == 2) ? d4.z : d4.w;
                unsigned u = (unsigned)(d - lo);
                if (u < NR) {
                    int s = src[base + k];
                    float3 m = lj_msg(x, s, d);
                    atomicAdd(&acc[3 * u + 0], m.x);
                    atomicAdd(&acc[3 * u + 1], m.y);
                    atomicAdd(&acc[3 * u + 2], m.z);
                }
            }
        } else {
            for (int e = base; e < slice_end; ++e) {
                int d = dst[e];
                unsigned u = (unsigned)(d - lo);
                if (u < NR) {
                    int s = src[e];
                    float3 m = lj_msg(x, s, d);
                    atomicAdd(&acc[3 * u + 0], m.x);
                    atomicAdd(&acc[3 * u + 1], m.y);
                    atomicAdd(&acc[3 * u + 2], m.z);
                }
            }
        }
    }
    __syncthreads();

    // Dump slab (coalesced float4 stores)
    float* slab = ws + (size_t)(r * gridDim.x + b) * S3;
    const float4* a4 = (const float4*)acc;
    float4* s4 = (float4*)slab;
    for (int i = tid; i < S3 / 4; i += 1024) s4[i] = a4[i];
}

// out[g] = sum_b ws[(r*bpr+b)*S3 + j] - GAMMA*v[g]
__global__ void merge_kernel(const float* __restrict__ ws,
                             const float* __restrict__ v,
                             float* __restrict__ out,
                             int n_out, int bpr)
{
    int g = blockIdx.x * blockDim.x + threadIdx.x;
    if (g >= n_out) return;
    int r = g / S3;
    int j = g - r * S3;
    const float* base = ws + (size_t)r * bpr * S3 + j;
    float sum = 0.0f;
    for (int b = 0; b < bpr; ++b) sum += base[(size_t)b * S3];
    out[g] = sum - GAMMA * v[g];
}

// ---------------- fallback path (round-1 style, if ws too small) -------------
__global__ void init_out_kernel(const float* __restrict__ v,
                                float* __restrict__ out, int n) {
    int i = blockIdx.x * blockDim.x + threadIdx.x;
    if (i < n) out[i] = -GAMMA * v[i];
}

__global__ void edge_atomic_kernel(const float* __restrict__ x,
                                   const int* __restrict__ src,
                                   const int* __restrict__ dst,
                                   float* __restrict__ out, int n_edges) {
    int t = blockIdx.x * blockDim.x + threadIdx.x;
    int base = t * 4;
    if (base + 3 < n_edges) {
        int4 s4 = *(const int4*)(src + base);
        int4 d4 = *(const int4*)(dst + base);
        #pragma unroll
        for (int k = 0; k < 4; ++k) {
            int s = (k == 0) ? s4.x : (k == 1) ? s4.y : (k == 2) ? s4.z : s4.w;
            int d = (k == 0) ? d4.x : (k == 1) ? d4.y : (k == 2) ? d4.z : d4.w;
            float3 m = lj_msg(x, s, d);
            unsafeAtomicAdd(&out[3 * d + 0], m.x);
            unsafeAtomicAdd(&out[3 * d + 1], m.y);
            unsafeAtomicAdd(&out[3 * d + 2], m.z);
        }
    } else {
        for (int e = base; e < n_edges; ++e) {
            int s = src[e], d = dst[e];
            float3 m = lj_msg(x, s, d);
            unsafeAtomicAdd(&out[3 * d + 0], m.x);
            unsafeAtomicAdd(&out[3 * d + 1], m.y);
            unsafeAtomicAdd(&out[3 * d + 2], m.z);
        }
    }
}

extern "C" void kernel_launch(void* const* d_in, const int* in_sizes, int n_in,
                              void* d_out, int out_size, void* d_ws, size_t ws_size,
                              hipStream_t stream) {
    const float* x   = (const float*)d_in[0];
    const float* v   = (const float*)d_in[1];
    const int*   src = (const int*)d_in[2];
    const int*   dst = (const int*)d_in[3];
    float* out = (float*)d_out;

    const int n_out = out_size;
    const int n_nodes = out_size / 3;
    const int n_edges = in_sizes[2];
    const int R = (n_nodes + NR - 1) / NR;

    // pick blocks-per-range so slabs fit in ws
    int bpr = 0;
    for (int cand : {24, 12, 6}) {
        size_t need = (size_t)R * cand * S3 * sizeof(float);
        if (need <= ws_size) { bpr = cand; break; }
    }

    if (bpr > 0) {
        int epb = ((n_edges + bpr - 1) / bpr + 3) & ~3;
        dim3 grid(bpr, R);
        edge_bin_kernel<<<grid, 1024, 0, stream>>>(x, src, dst, (float*)d_ws,
                                                   n_edges, epb);
        int blk = 256;
        merge_kernel<<<(n_out + blk - 1) / blk, blk, 0, stream>>>(
            (const float*)d_ws, v, out, n_out, bpr);
    } else {
        int blk = 256;
        init_out_kernel<<<(n_out + blk - 1) / blk, blk, 0, stream>>>(v, out, n_out);
        int n_t = (n_edges + 3) / 4;
        edge_atomic_kernel<<<(n_t + blk - 1) / blk, blk, 0, stream>>>(x, src, dst,
                                                                      out, n_edges);
    }
}